// Round 12
// baseline (2151.936 us; speedup 1.0000x reference)
//
#include <hip/hip_runtime.h>

#define NN 8192
#define EE 2048
#define BB 512
#define TT 128
#define HH 128
#define G3 384
#define MAXNNZ 256
#define MAXDEG 96
#define RD 32          // gx ring depth (t slots)

typedef __attribute__((ext_vector_type(8))) _Float16 f16x8;
typedef __attribute__((ext_vector_type(4))) float f32x4;

__device__ __forceinline__ float sigm(float x){ return 1.0f/(1.0f+__expf(-x)); }
__device__ __forceinline__ float tanhfast(float x){ return 2.0f/(1.0f+__expf(-2.0f*x)) - 1.0f; }

// ---- build per-edge nonzero index lists (Hbat is exactly binary) ----
__global__ __launch_bounds__(256)
void build_nnz(const float* __restrict__ Hb, int* __restrict__ idx, int* __restrict__ cnt){
  __shared__ int c;
  const int e = blockIdx.x;
  if (threadIdx.x == 0) c = 0;
  __syncthreads();
  const float* row = Hb + (size_t)e * NN;
  for (int n = threadIdx.x; n < NN; n += 256){
    if (row[n] != 0.0f){
      int p = atomicAdd(&c, 1);
      if (p < MAXNNZ) idx[e*MAXNNZ + p] = n;
    }
  }
  __syncthreads();
  if (threadIdx.x == 0) cnt[e] = (c < MAXNNZ ? c : MAXNNZ);
}

// ---- invert edge lists into per-node edge lists ----
__global__ __launch_bounds__(128)
void build_nodelists(const int* __restrict__ idx, const int* __restrict__ cnt,
                     int* __restrict__ ndeg, int* __restrict__ nidx){
  const int e = blockIdx.x;
  const int c = cnt[e];
  for (int k = threadIdx.x; k < c; k += 128){
    int n = idx[e*MAXNNZ + k];
    int p = atomicAdd(&ndeg[n], 1);
    if (p < MAXDEG) nidx[n*MAXDEG + p] = e;
  }
}

// ---- split (16*W) into fp16 hi/lo, row-major passthrough ----
__global__ __launch_bounds__(256)
void prep_w(const float* __restrict__ W, _Float16* __restrict__ whi,
            _Float16* __restrict__ wlo, int n){
  int i = blockIdx.x*256 + threadIdx.x;
  if (i >= n) return;
  float g = W[i] * 16.0f;
  _Float16 h = (_Float16)g;
  whi[i] = h;
  wlo[i] = (_Float16)(g - (float)h);
}

// ---- plain split X into fp16 hi/lo (no scale) ----
__global__ __launch_bounds__(256)
void prep_split(const float* __restrict__ X, _Float16* __restrict__ hi,
                _Float16* __restrict__ lo, int n){
  int i = blockIdx.x*256 + threadIdx.x;
  if (i >= n) return;
  float v = X[i];
  _Float16 h = (_Float16)v;
  hi[i] = h;
  lo[i] = (_Float16)(v - (float)h);
}

// ---- transpose + split (16*W) 128x128: wt[j,k] = 16*W[k,j] ----
__global__ __launch_bounds__(256)
void prep_wt(const float* __restrict__ W, _Float16* __restrict__ wt_hi,
             _Float16* __restrict__ wt_lo){
  int i = blockIdx.x*256 + threadIdx.x;   // 16384 total
  int k = i >> 7, j = i & 127;
  float g = W[i] * 16.0f;
  _Float16 h = (_Float16)g;
  wt_hi[j*HH + k] = h;
  wt_lo[j*HH + k] = (_Float16)(g - (float)h);
}

// ---- conv-phase MFMA GEMM on pre-split A: C[r,j] = rowscale[r]*(A@W + bias) ----
template<bool SCALE>
__global__ __launch_bounds__(256)
void mm128_mfma(const _Float16* __restrict__ Ahi, const _Float16* __restrict__ Alo,
                const _Float16* __restrict__ Bh, const _Float16* __restrict__ Bl,
                const float* __restrict__ bias, const float* __restrict__ rowscale,
                float* __restrict__ C)
{
  const int tid = threadIdx.x;
  const int w = tid >> 6, l = tid & 63;
  const int lm = l & 15, q = l >> 4;
  const int r0 = blockIdx.x * 32;
  const int n0 = w * 32;

  f32x4 acc[2][2];
  #pragma unroll
  for (int m=0;m<2;m++)
    #pragma unroll
    for (int n=0;n<2;n++) acc[m][n] = (f32x4){0.f,0.f,0.f,0.f};

  #pragma unroll 2
  for (int ks = 0; ks < 4; ++ks){
    const int kb = ks*32 + q*8;
    f16x8 ah[2], al[2];
    #pragma unroll
    for (int m=0;m<2;m++){
      const size_t ro = (size_t)(r0 + m*16 + lm)*HH + kb;
      ah[m] = *(const f16x8*)(Ahi + ro);
      al[m] = *(const f16x8*)(Alo + ro);
    }
    #pragma unroll
    for (int n=0;n<2;n++){
      const int j = n0 + n*16 + lm;
      f16x8 bh = *(const f16x8*)(Bh + (size_t)j*HH + kb);
      f16x8 bl = *(const f16x8*)(Bl + (size_t)j*HH + kb);
      #pragma unroll
      for (int m=0;m<2;m++){
        acc[m][n] = __builtin_amdgcn_mfma_f32_16x16x32_f16(ah[m], bh, acc[m][n], 0,0,0);
        acc[m][n] = __builtin_amdgcn_mfma_f32_16x16x32_f16(al[m], bh, acc[m][n], 0,0,0);
        acc[m][n] = __builtin_amdgcn_mfma_f32_16x16x32_f16(ah[m], bl, acc[m][n], 0,0,0);
      }
    }
  }
  #pragma unroll
  for (int n=0;n<2;n++){
    const int j = n0 + n*16 + lm;
    const float bv = bias[j];
    #pragma unroll
    for (int m=0;m<2;m++){
      #pragma unroll
      for (int i=0;i<4;i++){
        int r = r0 + m*16 + q*4 + i;
        float cv = acc[m][n][i]*(1.0f/16.0f) + bv;
        if (SCALE) cv *= rowscale[r];
        C[(size_t)r*HH + j] = cv;
      }
    }
  }
}

// ---- edge gather: Eb[e,:] = invDE[e] * sum_{n in edge e} Xs[n,:] ----
__global__ __launch_bounds__(128)
void edge_gather(const float* __restrict__ Xs, const int* __restrict__ idx,
                 const int* __restrict__ cnt, const float* __restrict__ invDE,
                 float* __restrict__ Eb){
  __shared__ int sidx[MAXNNZ];
  const int e = blockIdx.x, h = threadIdx.x;
  const int c = cnt[e];
  for (int k = h; k < c; k += 128) sidx[k] = idx[e*MAXNNZ + k];
  __syncthreads();
  float acc = 0.0f;
  int k = 0;
  for (; k + 4 <= c; k += 4){
    float a0 = Xs[(size_t)sidx[k+0]*HH + h];
    float a1 = Xs[(size_t)sidx[k+1]*HH + h];
    float a2 = Xs[(size_t)sidx[k+2]*HH + h];
    float a3 = Xs[(size_t)sidx[k+3]*HH + h];
    acc += (a0 + a1) + (a2 + a3);
  }
  for (; k < c; ++k) acc += Xs[(size_t)sidx[k]*HH + h];
  Eb[e*HH + h] = invDE[e] * acc;
}

// ---- node gather: v = DV2[n] * sum_{e ∋ n} Eb[e,:]; MODE1: split(relu(v)+poi), MODE2: fp32 v ----
template<int MODE>
__global__ __launch_bounds__(128)
void node_gather(const float* __restrict__ Eb, const int* __restrict__ nidx,
                 const int* __restrict__ ndeg, const float* __restrict__ DV2,
                 const float* __restrict__ poi, _Float16* __restrict__ ohi,
                 _Float16* __restrict__ olo, float* __restrict__ Xo){
  __shared__ int sidx[MAXDEG];
  const int n = blockIdx.x, h = threadIdx.x;
  int c = ndeg[n]; c = c < MAXDEG ? c : MAXDEG;
  for (int k = h; k < c; k += 128) sidx[k] = nidx[n*MAXDEG + k];
  __syncthreads();
  float acc = 0.0f;
  int k = 0;
  for (; k + 4 <= c; k += 4){
    float a0 = Eb[(size_t)sidx[k+0]*HH + h];
    float a1 = Eb[(size_t)sidx[k+1]*HH + h];
    float a2 = Eb[(size_t)sidx[k+2]*HH + h];
    float a3 = Eb[(size_t)sidx[k+3]*HH + h];
    acc += (a0 + a1) + (a2 + a3);
  }
  for (; k < c; ++k) acc += Eb[(size_t)sidx[k]*HH + h];
  float v = DV2[n] * acc;
  if (MODE == 1){
    float val = fmaxf(v, 0.0f) + poi[(size_t)n*HH + h];
    _Float16 hh = (_Float16)val;
    ohi[(size_t)n*HH + h] = hh;
    olo[(size_t)n*HH + h] = (_Float16)(val - (float)hh);
  } else {
    Xo[(size_t)n*HH + h] = v;
  }
}

// ---- gather emb rows -> fp16 hi/lo split only ----
__global__ __launch_bounds__(256)
void gather_emb(const float* __restrict__ X, const int* __restrict__ data,
                _Float16* __restrict__ aHi, _Float16* __restrict__ aLo){
  int r = blockIdx.x*2 + (threadIdx.x >> 7);
  int h = threadIdx.x & 127;
  int n = data[r];
  float v = X[(size_t)n*HH + h];
  size_t o = (size_t)r*HH + h;
  _Float16 hh = (_Float16)v;
  aHi[o] = hh;
  aLo[o] = (_Float16)(v - (float)hh);
}

// ---- pipelined 3-layer GRU: one block = 2 batches; 3 wave-groups = 3 layers,
// skewed by 16-step chunks. Group-local LDS-counter barriers; inter-group
// handoff via same-CU global A buffers + LDS progress flags.
__global__ __launch_bounds__(768)
void gru_pipe(const float* __restrict__ WhhAll, const float* __restrict__ bhhAll,
              const _Float16* __restrict__ WhiAll, const _Float16* __restrict__ WloAll,
              const float* __restrict__ bihAll, const int* __restrict__ lens,
              const _Float16* __restrict__ a0Hi, const _Float16* __restrict__ a0Lo,
              _Float16* __restrict__ a1Hi, _Float16* __restrict__ a1Lo,
              _Float16* __restrict__ a2Hi, _Float16* __restrict__ a2Lo,
              float* __restrict__ gxr, float* __restrict__ out)
{
  __shared__ _Float16 hbufs[3][2][16*HH];   // 24 KB
  __shared__ float ghTs[3][2][392];         // 9.4 KB
  __shared__ int prog[3];
  __shared__ int gbar[3];

  const int tid = threadIdx.x;
  const int g = tid >> 8;            // layer group 0..2
  const int gtid = tid & 255;
  const int lane = tid & 63;
  const int lm = lane & 15, q = lane >> 4;
  const int gw = gtid >> 6;          // wave within group 0..3
  const int p = blockIdx.x, b0 = 2*p;
  const int n0 = gw * 96;            // 96-col slab per wave

  if (tid < 3){ prog[tid] = 0; gbar[tid] = 0; }
  {
    unsigned int* z = (unsigned int*)&hbufs[0][0][0];
    #pragma unroll 1
    for (int i = tid; i < 3*2*16*HH/2; i += 768) z[i] = 0u;
  }
  __syncthreads();

  const int len0 = lens[b0], len1 = lens[b0+1];
  const int lenmax = len0;           // sorted descending
  const int nch = (lenmax + 15) >> 4;

  // Whh fragments for this group's layer (x16 scaled)
  const float* Whh = WhhAll + (size_t)g*G3*HH;
  f16x8 wf[6][4];
  #pragma unroll
  for (int j=0; j<6; ++j){
    const int col = n0 + j*16 + lm;
    const float* wr = Whh + (size_t)col*HH;
    #pragma unroll
    for (int ks=0; ks<4; ++ks){
      const int kb = ks*32 + q*8;
      float4 f0 = *(const float4*)(wr + kb);
      float4 f1 = *(const float4*)(wr + kb + 4);
      float fv[8] = {f0.x,f0.y,f0.z,f0.w,f1.x,f1.y,f1.z,f1.w};
      union { f16x8 v; _Float16 u[8]; } uu;
      #pragma unroll
      for (int jj=0;jj<8;jj++) uu.u[jj] = (_Float16)(fv[jj] * 16.0f);
      wf[j][ks] = uu.v;
    }
  }
  const float S = 1.0f/16.0f;

  // gate mapping: 256 threads = 2 batches x 128 dims
  const int gb = gtid >> 7, gd = gtid & 127;
  const float bRR = bihAll[g*G3 + gd]       + bhhAll[g*G3 + gd];
  const float bZZ = bihAll[g*G3 + 128 + gd] + bhhAll[g*G3 + 128 + gd];
  const float bi2 = bihAll[g*G3 + 256 + gd];
  const float bN  = bhhAll[g*G3 + 256 + gd];
  const int glen = gb ? len1 : len0;

  const _Float16* aInHi = (g==0) ? a0Hi : (g==1 ? a1Hi : a2Hi);
  const _Float16* aInLo = (g==0) ? a0Lo : (g==1 ? a1Lo : a2Lo);
  _Float16* aOutHi = (g==0) ? a1Hi : a2Hi;   // unused for g==2
  _Float16* aOutLo = (g==0) ? a1Lo : a2Lo;
  const size_t arow = ((size_t)(b0+gb)*TT)*HH + gd;   // per-thread row base

  float* gxr_blk = gxr + ((size_t)p*3 + g)*2*RD*G3;
  const float* gxrow = gxr_blk + (size_t)gb*RD*G3 + gd;

  const _Float16* WihHi = WhiAll + (size_t)g*G3*HH;
  const _Float16* WihLo = WloAll + (size_t)g*G3*HH;

  volatile int* vprog = prog;
  volatile int* vbar = gbar;
  int phase = 0;
  auto GSYNC = [&](){
    asm volatile("s_waitcnt lgkmcnt(0)" ::: "memory");
    ++phase;
    if (lane == 0) atomicAdd(&gbar[g], 1);
    while (vbar[g] < 4*phase) { }
  };

  float hp = 0.f, fo = 0.f;
  int cur = 0;

  #pragma unroll 1
  for (int ch = 0; ch < nch; ++ch){
    const int t0 = ch*16;
    const int tend = (t0+16 < lenmax) ? t0+16 : lenmax;

    // wait for producer layer's A rows
    if (g > 0){
      const int need = tend;
      while (vprog[g-1] < need) __builtin_amdgcn_s_sleep(2);
    }

    // ---- gx chunk GEMM: 16 t-rows x 384 cols, per batch ----
    #pragma unroll 1
    for (int bb = 0; bb < 2; ++bb){
      f32x4 acc[6];
      #pragma unroll
      for (int j=0;j<6;j++) acc[j] = (f32x4){0.f,0.f,0.f,0.f};
      #pragma unroll
      for (int ks = 0; ks < 4; ++ks){
        const int kb = ks*32 + q*8;
        const size_t ro = ((size_t)(b0+bb)*TT + t0 + lm)*HH + kb;
        f16x8 ah = *(const f16x8*)(aInHi + ro);
        f16x8 al = *(const f16x8*)(aInLo + ro);
        #pragma unroll
        for (int j=0;j<6;j++){
          const int col = n0 + j*16 + lm;
          f16x8 bh = *(const f16x8*)(WihHi + (size_t)col*HH + kb);
          f16x8 bl = *(const f16x8*)(WihLo + (size_t)col*HH + kb);
          acc[j] = __builtin_amdgcn_mfma_f32_16x16x32_f16(ah, bh, acc[j], 0,0,0);
          acc[j] = __builtin_amdgcn_mfma_f32_16x16x32_f16(al, bh, acc[j], 0,0,0);
          acc[j] = __builtin_amdgcn_mfma_f32_16x16x32_f16(ah, bl, acc[j], 0,0,0);
        }
      }
      float* gbase = gxr_blk + (size_t)bb*RD*G3;
      #pragma unroll
      for (int j=0;j<6;j++){
        #pragma unroll
        for (int i=0;i<4;i++){
          const int t = t0 + q*4 + i;
          gbase[(size_t)(t & (RD-1))*G3 + n0 + j*16 + lm] = acc[j][i];
        }
      }
    }
    asm volatile("s_waitcnt vmcnt(0)" ::: "memory");
    GSYNC();

    // load this chunk's first gx (+emb) values
    float xv0 = gxrow[(size_t)(t0 & (RD-1))*G3];
    float xv1 = gxrow[(size_t)(t0 & (RD-1))*G3 + 128];
    float xv2 = gxrow[(size_t)(t0 & (RD-1))*G3 + 256];
    float xe = 0.f;
    if (g < 2) xe = (float)a0Hi[arow + (size_t)t0*HH] + (float)a0Lo[arow + (size_t)t0*HH];

    // ---- 16 scan steps ----
    #pragma unroll 1
    for (int t = t0; t < tend; ++t){
      // phase A: gh MFMA (all 4 waves)
      f16x8 av[4];
      #pragma unroll
      for (int ks=0; ks<4; ++ks){
        int off = (lm*256 + ks*64 + q*16) ^ ((lm & 7) << 4);
        av[ks] = *(const f16x8*)((const char*)&hbufs[g][cur][0] + off);
      }
      // prefetch t+1 (within chunk only)
      float xn0=0.f, xn1=0.f, xn2=0.f, xen=0.f;
      const bool pf = (t+1 < tend);
      if (pf){
        const size_t ts1 = (size_t)((t+1) & (RD-1))*G3;
        xn0 = gxrow[ts1]; xn1 = gxrow[ts1 + 128]; xn2 = gxrow[ts1 + 256];
        if (g < 2) xen = (float)a0Hi[arow + (size_t)(t+1)*HH] + (float)a0Lo[arow + (size_t)(t+1)*HH];
      }
      f32x4 a[6];
      #pragma unroll
      for (int j=0;j<6;j++) a[j] = (f32x4){0.f,0.f,0.f,0.f};
      #pragma unroll
      for (int ks=0; ks<4; ++ks){
        #pragma unroll
        for (int j=0;j<6;j++)
          a[j] = __builtin_amdgcn_mfma_f32_16x16x32_f16(av[ks], wf[j][ks], a[j], 0,0,0);
      }
      if (q == 0){
        const int c0 = n0 + lm;
        #pragma unroll
        for (int j=0;j<6;j++){
          ghTs[g][0][c0 + j*16] = a[j][0];
          ghTs[g][1][c0 + j*16] = a[j][1];
        }
      }
      GSYNC();

      // phase B: gates (256 threads, one (batch,dim) each)
      {
        float gr = ghTs[g][gb][gd];
        float gz = ghTs[g][gb][128+gd];
        float gn = ghTs[g][gb][256+gd];
        float r = sigm((xv0 + gr)*S + bRR);
        float z = sigm((xv1 + gz)*S + bZZ);
        float n = tanhfast(xv2*S + bi2 + r*(gn*S + bN));
        float hnew = (1.0f - z)*n + z*hp;
        hp = hnew;
        int off = (gb*256 + gd*2) ^ (gb << 4);
        *(_Float16*)((char*)&hbufs[g][cur^1][0] + off) = (_Float16)hnew;
        if (g < 2){
          float aval = xe + fmaxf(hnew, 0.0f);
          _Float16 ah = (_Float16)aval;
          aOutHi[arow + (size_t)t*HH] = ah;
          aOutLo[arow + (size_t)t*HH] = (_Float16)(aval - (float)ah);
        } else {
          if (t == glen - 1) fo = tanhfast(hnew);
        }
      }
      xv0 = xn0; xv1 = xn1; xv2 = xn2; xe = xen;
      GSYNC();
      cur ^= 1;
    }

    // publish progress (A rows < tend complete)
    if (g < 2){
      asm volatile("s_waitcnt vmcnt(0)" ::: "memory");
      GSYNC();
      if (gtid == 0) vprog[g] = tend;
    }
  }

  if (g == 2)
    out[(size_t)(b0+gb)*HH + gd] = fo;
}

extern "C" void kernel_launch(void* const* d_in, const int* in_sizes, int n_in,
                              void* d_out, int out_size, void* d_ws, size_t ws_size,
                              hipStream_t stream)
{
  const float* Hb    = (const float*)d_in[0];
  const float* DV2   = (const float*)d_in[1];
  const float* invDE = (const float*)d_in[2];
  const int*   data  = (const int*)d_in[3];
  const int*   dlen  = (const int*)d_in[4];
  const float* poi   = (const float*)d_in[5];
  const float* w1    = (const float*)d_in[6];
  const float* b1    = (const float*)d_in[7];
  const float* w2    = (const float*)d_in[8];
  const float* b2    = (const float*)d_in[9];
  const float* Wih   = (const float*)d_in[10];
  const float* Whh   = (const float*)d_in[11];
  const float* bih   = (const float*)d_in[12];
  const float* bhh   = (const float*)d_in[13];
  float* out = (float*)d_out;

  float* ws  = (float*)d_ws;
  // gx ring region (75.5 MB); conv scratch aliases inside it (used strictly before gru_pipe)
  float* gxr = ws;                                   // 256 * 3*2*RD*G3 floats
  float* x1s  = gxr;                                 // N*H
  float* x3s  = x1s + (size_t)NN*HH;                 // N*H
  float* x4   = x3s + (size_t)NN*HH;                 // N*H
  float* ebuf = x4  + (size_t)NN*HH;                 // E*H
  int* idx  = (int*)(ebuf + (size_t)EE*HH);          // E*MAXNNZ
  int* cnt  = idx + (size_t)EE*MAXNNZ;               // E
  int* ndeg = cnt + EE;                              // N
  int* nidx = ndeg + NN;                             // N*MAXDEG

  _Float16* a0Hi = (_Float16*)(gxr + (size_t)256*3*2*RD*G3);
  _Float16* a0Lo = a0Hi + (size_t)BB*TT*HH;
  _Float16* a1Hi = a0Lo + (size_t)BB*TT*HH;
  _Float16* a1Lo = a1Hi + (size_t)BB*TT*HH;
  _Float16* a2Hi = a1Lo + (size_t)BB*TT*HH;
  _Float16* a2Lo = a2Hi + (size_t)BB*TT*HH;
  _Float16* x2hi = a2Lo + (size_t)BB*TT*HH;          // N*H
  _Float16* x2lo = x2hi + (size_t)NN*HH;
  _Float16* pHi  = x2lo + (size_t)NN*HH;             // N*H
  _Float16* pLo  = pHi + (size_t)NN*HH;
  _Float16* Whi  = pLo + (size_t)NN*HH;              // 3*384*128
  _Float16* Wlo  = Whi + (size_t)3*G3*HH;
  _Float16* w1th = Wlo + (size_t)3*G3*HH;            // 128*128 each
  _Float16* w1tl = w1th + (size_t)HH*HH;
  _Float16* w2th = w1tl + (size_t)HH*HH;
  _Float16* w2tl = w2th + (size_t)HH*HH;

  // ---- prep ----
  hipMemsetAsync(ndeg, 0, NN*sizeof(int), stream);
  build_nnz<<<EE, 256, 0, stream>>>(Hb, idx, cnt);
  build_nodelists<<<EE, 128, 0, stream>>>(idx, cnt, ndeg, nidx);
  prep_w<<<(3*G3*HH + 255)/256, 256, 0, stream>>>(Wih, Whi, Wlo, 3*G3*HH);
  prep_wt<<<HH*HH/256, 256, 0, stream>>>(w1, w1th, w1tl);
  prep_wt<<<HH*HH/256, 256, 0, stream>>>(w2, w2th, w2tl);
  prep_split<<<NN*HH/256, 256, 0, stream>>>(poi, pHi, pLo, NN*HH);

  // ---- hypergraph conv phase ----
  mm128_mfma<true><<<NN/32, 256, 0, stream>>>(pHi, pLo, w1th, w1tl, b1, DV2, x1s);
  edge_gather<<<EE, 128, 0, stream>>>(x1s, idx, cnt, invDE, ebuf);
  node_gather<1><<<NN, 128, 0, stream>>>(ebuf, nidx, ndeg, DV2, poi, x2hi, x2lo, (float*)nullptr);
  mm128_mfma<true><<<NN/32, 256, 0, stream>>>(x2hi, x2lo, w2th, w2tl, b2, DV2, x3s);
  edge_gather<<<EE, 128, 0, stream>>>(x3s, idx, cnt, invDE, ebuf);
  node_gather<2><<<NN, 128, 0, stream>>>(ebuf, nidx, ndeg, DV2, (const float*)nullptr,
                                         (_Float16*)nullptr, (_Float16*)nullptr, x4);
  gather_emb<<<BB*TT/2, 256, 0, stream>>>(x4, data, a0Hi, a0Lo);

  // ---- pipelined 3-layer GRU stack ----
  gru_pipe<<<BB/2, 768, 0, stream>>>(Whh, bhh, Whi, Wlo, bih, dlen,
                                     a0Hi, a0Lo, a1Hi, a1Lo, a2Hi, a2Lo,
                                     gxr, out);
}

// Round 13
// 645.409 us; speedup vs baseline: 3.3342x; 3.3342x over previous
//
#include <hip/hip_runtime.h>

#define NN 8192
#define EE 2048
#define BB 512
#define TT 128
#define HH 128
#define G3 384
#define MAXNNZ 256
#define MAXDEG 96

typedef __attribute__((ext_vector_type(8))) _Float16 f16x8;
typedef __attribute__((ext_vector_type(4))) float f32x4;

__device__ __forceinline__ float sigm(float x){ return 1.0f/(1.0f+__expf(-x)); }
__device__ __forceinline__ float tanhfast(float x){ return 2.0f/(1.0f+__expf(-2.0f*x)) - 1.0f; }

// barrier ordering LDS only; global loads/stores stay in flight.
__device__ __forceinline__ void bar_lds(){
  __builtin_amdgcn_sched_barrier(0);
  asm volatile("s_waitcnt lgkmcnt(0)\n\ts_barrier" ::: "memory");
  __builtin_amdgcn_sched_barrier(0);
}

// ---- build per-edge nonzero index lists (Hbat is exactly binary) ----
__global__ __launch_bounds__(256)
void build_nnz(const float* __restrict__ Hb, int* __restrict__ idx, int* __restrict__ cnt){
  __shared__ int c;
  const int e = blockIdx.x;
  if (threadIdx.x == 0) c = 0;
  __syncthreads();
  const float* row = Hb + (size_t)e * NN;
  for (int n = threadIdx.x; n < NN; n += 256){
    if (row[n] != 0.0f){
      int p = atomicAdd(&c, 1);
      if (p < MAXNNZ) idx[e*MAXNNZ + p] = n;
    }
  }
  __syncthreads();
  if (threadIdx.x == 0) cnt[e] = (c < MAXNNZ ? c : MAXNNZ);
}

// ---- invert edge lists into per-node edge lists ----
__global__ __launch_bounds__(128)
void build_nodelists(const int* __restrict__ idx, const int* __restrict__ cnt,
                     int* __restrict__ ndeg, int* __restrict__ nidx){
  const int e = blockIdx.x;
  const int c = cnt[e];
  for (int k = threadIdx.x; k < c; k += 128){
    int n = idx[e*MAXNNZ + k];
    int p = atomicAdd(&ndeg[n], 1);
    if (p < MAXDEG) nidx[n*MAXDEG + p] = e;
  }
}

// ---- split (16*W) into fp16 hi/lo, row-major passthrough ----
__global__ __launch_bounds__(256)
void prep_w(const float* __restrict__ W, _Float16* __restrict__ whi,
            _Float16* __restrict__ wlo, int n){
  int i = blockIdx.x*256 + threadIdx.x;
  if (i >= n) return;
  float g = W[i] * 16.0f;
  _Float16 h = (_Float16)g;
  whi[i] = h;
  wlo[i] = (_Float16)(g - (float)h);
}

// ---- plain split X into fp16 hi/lo (no scale) ----
__global__ __launch_bounds__(256)
void prep_split(const float* __restrict__ X, _Float16* __restrict__ hi,
                _Float16* __restrict__ lo, int n){
  int i = blockIdx.x*256 + threadIdx.x;
  if (i >= n) return;
  float v = X[i];
  _Float16 h = (_Float16)v;
  hi[i] = h;
  lo[i] = (_Float16)(v - (float)h);
}

// ---- transpose + split (16*W) 128x128: wt[j,k] = 16*W[k,j] ----
__global__ __launch_bounds__(256)
void prep_wt(const float* __restrict__ W, _Float16* __restrict__ wt_hi,
             _Float16* __restrict__ wt_lo){
  int i = blockIdx.x*256 + threadIdx.x;   // 16384 total
  int k = i >> 7, j = i & 127;
  float g = W[i] * 16.0f;
  _Float16 h = (_Float16)g;
  wt_hi[j*HH + k] = h;
  wt_lo[j*HH + k] = (_Float16)(g - (float)h);
}

// ---- conv-phase MFMA GEMM on pre-split A: C[r,j] = rowscale[r]*(A@W + bias) ----
template<bool SCALE>
__global__ __launch_bounds__(256)
void mm128_mfma(const _Float16* __restrict__ Ahi, const _Float16* __restrict__ Alo,
                const _Float16* __restrict__ Bh, const _Float16* __restrict__ Bl,
                const float* __restrict__ bias, const float* __restrict__ rowscale,
                float* __restrict__ C)
{
  const int tid = threadIdx.x;
  const int w = tid >> 6, l = tid & 63;
  const int lm = l & 15, q = l >> 4;
  const int r0 = blockIdx.x * 32;
  const int n0 = w * 32;

  f32x4 acc[2][2];
  #pragma unroll
  for (int m=0;m<2;m++)
    #pragma unroll
    for (int n=0;n<2;n++) acc[m][n] = (f32x4){0.f,0.f,0.f,0.f};

  #pragma unroll 2
  for (int ks = 0; ks < 4; ++ks){
    const int kb = ks*32 + q*8;
    f16x8 ah[2], al[2];
    #pragma unroll
    for (int m=0;m<2;m++){
      const size_t ro = (size_t)(r0 + m*16 + lm)*HH + kb;
      ah[m] = *(const f16x8*)(Ahi + ro);
      al[m] = *(const f16x8*)(Alo + ro);
    }
    #pragma unroll
    for (int n=0;n<2;n++){
      const int j = n0 + n*16 + lm;
      f16x8 bh = *(const f16x8*)(Bh + (size_t)j*HH + kb);
      f16x8 bl = *(const f16x8*)(Bl + (size_t)j*HH + kb);
      #pragma unroll
      for (int m=0;m<2;m++){
        acc[m][n] = __builtin_amdgcn_mfma_f32_16x16x32_f16(ah[m], bh, acc[m][n], 0,0,0);
        acc[m][n] = __builtin_amdgcn_mfma_f32_16x16x32_f16(al[m], bh, acc[m][n], 0,0,0);
        acc[m][n] = __builtin_amdgcn_mfma_f32_16x16x32_f16(ah[m], bl, acc[m][n], 0,0,0);
      }
    }
  }
  #pragma unroll
  for (int n=0;n<2;n++){
    const int j = n0 + n*16 + lm;
    const float bv = bias[j];
    #pragma unroll
    for (int m=0;m<2;m++){
      #pragma unroll
      for (int i=0;i<4;i++){
        int r = r0 + m*16 + q*4 + i;
        float cv = acc[m][n][i]*(1.0f/16.0f) + bv;
        if (SCALE) cv *= rowscale[r];
        C[(size_t)r*HH + j] = cv;
      }
    }
  }
}

// ---- edge gather: Eb[e,:] = invDE[e] * sum_{n in edge e} Xs[n,:] ----
__global__ __launch_bounds__(128)
void edge_gather(const float* __restrict__ Xs, const int* __restrict__ idx,
                 const int* __restrict__ cnt, const float* __restrict__ invDE,
                 float* __restrict__ Eb){
  __shared__ int sidx[MAXNNZ];
  const int e = blockIdx.x, h = threadIdx.x;
  const int c = cnt[e];
  for (int k = h; k < c; k += 128) sidx[k] = idx[e*MAXNNZ + k];
  __syncthreads();
  float acc = 0.0f;
  int k = 0;
  for (; k + 4 <= c; k += 4){
    float a0 = Xs[(size_t)sidx[k+0]*HH + h];
    float a1 = Xs[(size_t)sidx[k+1]*HH + h];
    float a2 = Xs[(size_t)sidx[k+2]*HH + h];
    float a3 = Xs[(size_t)sidx[k+3]*HH + h];
    acc += (a0 + a1) + (a2 + a3);
  }
  for (; k < c; ++k) acc += Xs[(size_t)sidx[k]*HH + h];
  Eb[e*HH + h] = invDE[e] * acc;
}

// ---- node gather: v = DV2[n] * sum_{e ∋ n} Eb[e,:]; MODE1: split(relu(v)+poi), MODE2: fp32 v ----
template<int MODE>
__global__ __launch_bounds__(128)
void node_gather(const float* __restrict__ Eb, const int* __restrict__ nidx,
                 const int* __restrict__ ndeg, const float* __restrict__ DV2,
                 const float* __restrict__ poi, _Float16* __restrict__ ohi,
                 _Float16* __restrict__ olo, float* __restrict__ Xo){
  __shared__ int sidx[MAXDEG];
  const int n = blockIdx.x, h = threadIdx.x;
  int c = ndeg[n]; c = c < MAXDEG ? c : MAXDEG;
  for (int k = h; k < c; k += 128) sidx[k] = nidx[n*MAXDEG + k];
  __syncthreads();
  float acc = 0.0f;
  int k = 0;
  for (; k + 4 <= c; k += 4){
    float a0 = Eb[(size_t)sidx[k+0]*HH + h];
    float a1 = Eb[(size_t)sidx[k+1]*HH + h];
    float a2 = Eb[(size_t)sidx[k+2]*HH + h];
    float a3 = Eb[(size_t)sidx[k+3]*HH + h];
    acc += (a0 + a1) + (a2 + a3);
  }
  for (; k < c; ++k) acc += Eb[(size_t)sidx[k]*HH + h];
  float v = DV2[n] * acc;
  if (MODE == 1){
    float val = fmaxf(v, 0.0f) + poi[(size_t)n*HH + h];
    _Float16 hh = (_Float16)val;
    ohi[(size_t)n*HH + h] = hh;
    olo[(size_t)n*HH + h] = (_Float16)(val - (float)hh);
  } else {
    Xo[(size_t)n*HH + h] = v;
  }
}

// ---- gather emb rows -> fp16 hi/lo split (layer-0 A operand; also the residual source) ----
__global__ __launch_bounds__(256)
void gather_emb(const float* __restrict__ X, const int* __restrict__ data,
                _Float16* __restrict__ aHi, _Float16* __restrict__ aLo){
  int r = blockIdx.x*2 + (threadIdx.x >> 7);
  int h = threadIdx.x & 127;
  int n = data[r];
  float v = X[(size_t)n*HH + h];
  size_t o = (size_t)r*HH + h;
  _Float16 hh = (_Float16)v;
  aHi[o] = hh;
  aLo[o] = (_Float16)(v - (float)hh);
}

// ---- fused 3-layer GRU v2: one block = 2 batches; gx lives in a 2-slot LDS ring;
// next chunk's gx GEMM is interleaved into the scan steps (1 slice per step).
__global__ __launch_bounds__(512, 1)
void gru_fused2(const float* __restrict__ WhhAll, const float* __restrict__ bhhAll,
                const _Float16* __restrict__ WhiAll, const _Float16* __restrict__ WloAll,
                const float* __restrict__ bihAll, const int* __restrict__ lens,
                const _Float16* __restrict__ a0Hi, const _Float16* __restrict__ a0Lo,
                _Float16* __restrict__ aAHi, _Float16* __restrict__ aALo,
                _Float16* __restrict__ aBHi, _Float16* __restrict__ aBLo,
                float* __restrict__ out)
{
  __shared__ _Float16 hbuf[2][16*HH];     // 8 KB
  __shared__ float ghT[2][392];           // 3.1 KB
  __shared__ float ring[2][2][16][G3];    // 96 KB: [slot][batch][t%16][col]

  const int tid = threadIdx.x;
  const int w = tid >> 6, lane = tid & 63;
  const int lm = lane & 15, q = lane >> 4;
  const int b0 = blockIdx.x * 2;
  const int n0 = w * 48;                  // wave's 48-col slab (8 waves = 384)

  const int len0 = lens[b0], len1 = lens[b0+1];
  const int lenmax = len0;                // sorted descending
  const int nch = (lenmax + 15) >> 4;

  const int gb = (tid < 256) ? (tid >> 7) : 0;
  const int gd = tid & 127;
  const int glen = gb ? len1 : len0;
  const size_t eb = ((size_t)(b0+gb)*TT)*HH + gd;

  const float S = 1.0f/16.0f;

  #pragma unroll 1
  for (int l = 0; l < 3; ++l){
    const bool fin = (l == 2);
    const _Float16* Whi = WhiAll + (size_t)l*G3*HH;
    const _Float16* Wlo = WloAll + (size_t)l*G3*HH;
    const float* bih = bihAll + l*G3;
    const float* Whh = WhhAll + (size_t)l*G3*HH;
    const float* bhh = bhhAll + l*G3;
    const _Float16* aInHi = (l==0) ? a0Hi : (l==1 ? aAHi : aBHi);
    const _Float16* aInLo = (l==0) ? a0Lo : (l==1 ? aALo : aBLo);
    _Float16* aOutHi = (l==0) ? aAHi : aBHi;
    _Float16* aOutLo = (l==0) ? aALo : aBLo;

    const float bv0 = bih[n0+lm], bv1 = bih[n0+16+lm], bv2 = bih[n0+32+lm];

    // Whh fragments (B operand), wave w: cols n0 + {0,16,32} + lm  (48 VGPR)
    f16x8 wf[3][4];
    #pragma unroll
    for (int n=0; n<3; ++n){
      const float* wr = Whh + (size_t)(n0 + n*16 + lm)*HH;
      #pragma unroll
      for (int ks=0; ks<4; ++ks){
        const int kb = ks*32 + q*8;
        float4 f0 = *(const float4*)(wr + kb);
        float4 f1 = *(const float4*)(wr + kb + 4);
        float fv[8] = {f0.x,f0.y,f0.z,f0.w,f1.x,f1.y,f1.z,f1.w};
        union { f16x8 v; _Float16 u[8]; } uu;
        #pragma unroll
        for (int j=0;j<8;j++) uu.u[j] = (_Float16)(fv[j] * 16.0f);
        wf[n][ks] = uu.v;
      }
    }
    const float bR = bhh[gd], bZ = bhh[HH+gd], bN = bhh[2*HH+gd];

    // gx slice state
    f16x8 gah, gal, gb0h, gb0l, gb1h, gb1l, gb2h, gb2l;
    f32x4 ag0 = (f32x4){0.f,0.f,0.f,0.f}, ag1 = ag0, ag2 = ag0;

    auto GXLOAD = [&](int chn2, int p){
      const int bb = p >> 2, ks = p & 3, kb = ks*32 + q*8;
      const size_t ro = ((size_t)(b0+bb)*TT + chn2*16 + lm)*HH + kb;
      gah = *(const f16x8*)(aInHi + ro);
      gal = *(const f16x8*)(aInLo + ro);
      const size_t wb = (size_t)(n0+lm)*HH + kb;
      gb0h = *(const f16x8*)(Whi + wb);
      gb0l = *(const f16x8*)(Wlo + wb);
      gb1h = *(const f16x8*)(Whi + wb + (size_t)16*HH);
      gb1l = *(const f16x8*)(Wlo + wb + (size_t)16*HH);
      gb2h = *(const f16x8*)(Whi + wb + (size_t)32*HH);
      gb2l = *(const f16x8*)(Wlo + wb + (size_t)32*HH);
    };
    auto GXMFMA = [&](){
      ag0 = __builtin_amdgcn_mfma_f32_16x16x32_f16(gah, gb0h, ag0, 0,0,0);
      ag0 = __builtin_amdgcn_mfma_f32_16x16x32_f16(gal, gb0h, ag0, 0,0,0);
      ag0 = __builtin_amdgcn_mfma_f32_16x16x32_f16(gah, gb0l, ag0, 0,0,0);
      ag1 = __builtin_amdgcn_mfma_f32_16x16x32_f16(gah, gb1h, ag1, 0,0,0);
      ag1 = __builtin_amdgcn_mfma_f32_16x16x32_f16(gal, gb1h, ag1, 0,0,0);
      ag1 = __builtin_amdgcn_mfma_f32_16x16x32_f16(gah, gb1l, ag1, 0,0,0);
      ag2 = __builtin_amdgcn_mfma_f32_16x16x32_f16(gah, gb2h, ag2, 0,0,0);
      ag2 = __builtin_amdgcn_mfma_f32_16x16x32_f16(gal, gb2h, ag2, 0,0,0);
      ag2 = __builtin_amdgcn_mfma_f32_16x16x32_f16(gah, gb2l, ag2, 0,0,0);
    };
    auto GXWRITE = [&](int chn2, int bb){
      #pragma unroll
      for (int i=0;i<4;i++){
        ring[chn2&1][bb][q*4+i][n0+lm]      = ag0[i]*S + bv0;
        ring[chn2&1][bb][q*4+i][n0+16+lm]   = ag1[i]*S + bv1;
        ring[chn2&1][bb][q*4+i][n0+32+lm]   = ag2[i]*S + bv2;
      }
      ag0 = (f32x4){0.f,0.f,0.f,0.f}; ag1 = ag0; ag2 = ag0;
    };

    {   // zero both h buffers (rows 2..15 remain zero)
      unsigned int* z = (unsigned int*)&hbuf[0][0];
      #pragma unroll 1
      for (int i = tid; i < 2*16*HH/2; i += 512) z[i] = 0u;
    }

    // prologue: gx chunk 0 into ring slot 0
    #pragma unroll 1
    for (int p = 0; p < 8; ++p){
      GXLOAD(0, p);
      GXMFMA();
      if (p == 3) GXWRITE(0, 0);
      if (p == 7) GXWRITE(0, 1);
    }
    __syncthreads();

    float xe = 0.f, hp = 0.f, fo = 0.f;
    if (tid < 256 && !fin)
      xe = (float)a0Hi[eb] + (float)a0Lo[eb];

    int cur = 0;
    #pragma unroll 1
    for (int t = 0; t < lenmax; ++t){
      const int s = t & 15;
      const int chn = (t >> 4) + 1;
      const bool doGx = chn < nch;

      // phase A: h A-frags + gx(t) from ring + xe prefetch + gx slice
      f16x8 av[4];
      #pragma unroll
      for (int ks=0; ks<4; ++ks){
        int off = (lm*256 + ks*64 + q*16) ^ ((lm & 7) << 4);
        av[ks] = *(const f16x8*)((const char*)&hbuf[cur][0] + off);
      }
      float xv0=0.f, xv1=0.f, xv2=0.f, xen=0.f;
      if (tid < 256){
        const float* rp = &ring[(t>>4)&1][gb][s][0];
        xv0 = rp[gd]; xv1 = rp[128+gd]; xv2 = rp[256+gd];
        if (!fin){
          int tp = (t+1 < lenmax) ? t+1 : t;
          xen = (float)a0Hi[eb + (size_t)tp*HH] + (float)a0Lo[eb + (size_t)tp*HH];
        }
      }
      if (doGx && !(s & 1)) GXLOAD(chn, s >> 1);

      f32x4 aGH0 = (f32x4){0.f,0.f,0.f,0.f}, aGH1 = aGH0, aGH2 = aGH0;
      #pragma unroll
      for (int ks=0; ks<4; ++ks){
        aGH0 = __builtin_amdgcn_mfma_f32_16x16x32_f16(av[ks], wf[0][ks], aGH0, 0,0,0);
        aGH1 = __builtin_amdgcn_mfma_f32_16x16x32_f16(av[ks], wf[1][ks], aGH1, 0,0,0);
        aGH2 = __builtin_amdgcn_mfma_f32_16x16x32_f16(av[ks], wf[2][ks], aGH2, 0,0,0);
      }
      if (doGx && (s & 1)){
        GXMFMA();
        if (s == 7)  GXWRITE(chn, 0);
        else if (s == 15) GXWRITE(chn, 1);
      }
      if (q == 0){   // rows 0,1 = batches 0,1
        const int c0 = n0 + lm;
        ghT[0][c0]      = aGH0[0];  ghT[1][c0]      = aGH0[1];
        ghT[0][c0+16]   = aGH1[0];  ghT[1][c0+16]   = aGH1[1];
        ghT[0][c0+32]   = aGH2[0];  ghT[1][c0+32]   = aGH2[1];
      }
      bar_lds();

      // phase B: one gate-triple per thread (tid < 256)
      if (tid < 256){
        float gr = ghT[gb][gd], gz = ghT[gb][128+gd], gn = ghT[gb][256+gd];
        float r = sigm(xv0 + gr*S + bR);
        float z = sigm(xv1 + gz*S + bZ);
        float n = tanhfast(xv2 + r*(gn*S + bN));
        float hnew = (1.0f - z)*n + z*hp;
        hp = hnew;
        int off = (gb*256 + gd*2) ^ (gb << 4);
        *(_Float16*)((char*)&hbuf[cur^1][0] + off) = (_Float16)hnew;
        if (!fin){
          float a = xe + fmaxf(hnew, 0.0f);
          _Float16 ah = (_Float16)a;
          aOutHi[eb + (size_t)t*HH] = ah;
          aOutLo[eb + (size_t)t*HH] = (_Float16)(a - (float)ah);
        } else {
          if (t == glen - 1) fo = tanhfast(hnew);
        }
      }
      xe = xen;
      bar_lds();
      cur ^= 1;
    }

    if (fin){
      if (tid < 256)
        out[(size_t)(b0+gb)*HH + gd] = fo;
    } else {
      __syncthreads();   // drain aOut stores before next layer reads them
    }
  }
}

extern "C" void kernel_launch(void* const* d_in, const int* in_sizes, int n_in,
                              void* d_out, int out_size, void* d_ws, size_t ws_size,
                              hipStream_t stream)
{
  const float* Hb    = (const float*)d_in[0];
  const float* DV2   = (const float*)d_in[1];
  const float* invDE = (const float*)d_in[2];
  const int*   data  = (const int*)d_in[3];
  const int*   dlen  = (const int*)d_in[4];
  const float* poi   = (const float*)d_in[5];
  const float* w1    = (const float*)d_in[6];
  const float* b1    = (const float*)d_in[7];
  const float* w2    = (const float*)d_in[8];
  const float* b2    = (const float*)d_in[9];
  const float* Wih   = (const float*)d_in[10];
  const float* Whh   = (const float*)d_in[11];
  const float* bih   = (const float*)d_in[12];
  const float* bhh   = (const float*)d_in[13];
  float* out = (float*)d_out;

  float* ws   = (float*)d_ws;
  float* x1s  = ws;                          // N*H f32
  float* x3s  = x1s + (size_t)NN*HH;         // N*H f32
  float* x4   = x3s + (size_t)NN*HH;         // N*H f32
  float* ebuf = x4  + (size_t)NN*HH;         // E*H f32
  _Float16* a0Hi = (_Float16*)(ebuf + (size_t)EE*HH);   // B*T*H each
  _Float16* a0Lo = a0Hi + (size_t)BB*TT*HH;
  _Float16* aAHi = a0Lo + (size_t)BB*TT*HH;
  _Float16* aALo = aAHi + (size_t)BB*TT*HH;
  _Float16* aBHi = aALo + (size_t)BB*TT*HH;
  _Float16* aBLo = aBHi + (size_t)BB*TT*HH;
  _Float16* x2hi = aBLo + (size_t)BB*TT*HH;  // N*H
  _Float16* x2lo = x2hi + (size_t)NN*HH;
  _Float16* pHi  = x2lo + (size_t)NN*HH;     // N*H
  _Float16* pLo  = pHi + (size_t)NN*HH;
  _Float16* Whi  = pLo + (size_t)NN*HH;      // 3*384*128
  _Float16* Wlo  = Whi + (size_t)3*G3*HH;
  _Float16* w1th = Wlo + (size_t)3*G3*HH;    // 128*128 each
  _Float16* w1tl = w1th + (size_t)HH*HH;
  _Float16* w2th = w1tl + (size_t)HH*HH;
  _Float16* w2tl = w2th + (size_t)HH*HH;
  int* idx  = (int*)(w2tl + (size_t)HH*HH);  // E*MAXNNZ
  int* cnt  = idx + (size_t)EE*MAXNNZ;       // E
  int* ndeg = cnt + EE;                      // N
  int* nidx = ndeg + NN;                     // N*MAXDEG

  // ---- prep ----
  hipMemsetAsync(ndeg, 0, NN*sizeof(int), stream);
  build_nnz<<<EE, 256, 0, stream>>>(Hb, idx, cnt);
  build_nodelists<<<EE, 128, 0, stream>>>(idx, cnt, ndeg, nidx);
  prep_w<<<(3*G3*HH + 255)/256, 256, 0, stream>>>(Wih, Whi, Wlo, 3*G3*HH);
  prep_wt<<<HH*HH/256, 256, 0, stream>>>(w1, w1th, w1tl);
  prep_wt<<<HH*HH/256, 256, 0, stream>>>(w2, w2th, w2tl);
  prep_split<<<NN*HH/256, 256, 0, stream>>>(poi, pHi, pLo, NN*HH);

  // ---- hypergraph conv phase ----
  mm128_mfma<true><<<NN/32, 256, 0, stream>>>(pHi, pLo, w1th, w1tl, b1, DV2, x1s);
  edge_gather<<<EE, 128, 0, stream>>>(x1s, idx, cnt, invDE, ebuf);
  node_gather<1><<<NN, 128, 0, stream>>>(ebuf, nidx, ndeg, DV2, poi, x2hi, x2lo, (float*)nullptr);
  mm128_mfma<true><<<NN/32, 256, 0, stream>>>(x2hi, x2lo, w2th, w2tl, b2, DV2, x3s);
  edge_gather<<<EE, 128, 0, stream>>>(x3s, idx, cnt, invDE, ebuf);
  node_gather<2><<<NN, 128, 0, stream>>>(ebuf, nidx, ndeg, DV2, (const float*)nullptr,
                                         (_Float16*)nullptr, (_Float16*)nullptr, x4);
  gather_emb<<<BB*TT/2, 256, 0, stream>>>(x4, data, a0Hi, a0Lo);

  // ---- fused 3-layer GRU stack (LDS gx ring + interleaved gx) ----
  gru_fused2<<<BB/2, 512, 0, stream>>>(Whh, bhh, Whi, Wlo, bih, dlen,
                                       a0Hi, a0Lo, aAHi, aALo, aBHi, aBLo, out);
}